// Round 1
// 685.102 us; speedup vs baseline: 1.2605x; 1.2605x over previous
//
#include <hip/hip_runtime.h>
#include <math.h>

// ResidualVQ fused forward, MI355X (gfx950) — round 5.
// R4 post-mortem: rvq_main 750us, VALUBusy 26.5%, LDS_BANK_CONFLICT 4.6e7,
// occupancy 21.5% -> LDS-throughput + latency bound, not HBM/compute.
// R5: distance loop reads cbn32 direct from L2 (no staging, no conflicts),
// 4 tokens/thread, shfl_xor top-2 merge, GEMM acc[4][4] with 2 LDS reads per
// 16 FMA + global_load_lds B staging, 34KB LDS -> 4 blocks/CU (full residency).

#define TAU 3e-4f

// ws byte offsets
#define WS_WACC   0
#define WS_HV64   64
#define WS_G64    2048
#define WS_CBN64  133120
#define WS_CBN32  1247232
#define WS_G32    1902592
#define WS_HV32   1968128
#define WS_BMAT   1968640
#define WS_SBU    2492928

__device__ __forceinline__ void gload_lds16(const void* g, void* l) {
    __builtin_amdgcn_global_load_lds(
        (const __attribute__((address_space(1))) void*)g,
        (__attribute__((address_space(3))) void*)l, 16, 0, 0);
}

// ============================ prep1 ============================
// blocks: [0,32) cbn | [32,160) bmat | [160,192) sbu | 192 zero
__global__ void __launch_bounds__(256) rvq_prep1(
    const float* __restrict__ cb, const float* __restrict__ Wd,
    const float* __restrict__ bu,
    double* __restrict__ cbn64, float* __restrict__ cbn32,
    float* __restrict__ Bmat, double* __restrict__ sbu,
    double* __restrict__ wacc)
{
    const int b = blockIdx.x, t = threadIdx.x;
    if (b < 32) {                       // normalized codebook fp64+fp32
        const int idx = b * 256 + t;    // l*1024+k
        const float* cp = cb + (size_t)idx * 16;
        double v[16]; double n = 0.0;
#pragma unroll
        for (int c = 0; c < 16; ++c) { v[c] = (double)cp[c]; n = fma(v[c], v[c], n); }
        const double iv = 1.0 / fmax(sqrt(n), 1e-12);
        double* r64 = cbn64 + (size_t)idx * 17;
        float*  r32 = cbn32 + (size_t)idx * 20;
        double c2 = 0.0;
#pragma unroll
        for (int c = 0; c < 16; ++c) {
            const double x = v[c] * iv;
            c2 = fma(x, x, c2);
            r64[c] = x; r32[c] = (float)x;
        }
        r64[16] = c2;
        r32[16] = (float)c2; r32[17] = 0.f; r32[18] = 0.f; r32[19] = 0.f;
    } else if (b < 160) {               // Bmat[d][ic] = Wd[ic][d]
        const int ic = b - 32;
        const int d0 = t * 4;
        const float4 v = *(const float4*)(Wd + (size_t)ic * 1024 + d0);
        Bmat[(size_t)(d0 + 0) * 128 + ic] = v.x;
        Bmat[(size_t)(d0 + 1) * 128 + ic] = v.y;
        Bmat[(size_t)(d0 + 2) * 128 + ic] = v.z;
        Bmat[(size_t)(d0 + 3) * 128 + ic] = v.w;
    } else if (b < 192) {               // sbu[i][d] = sum_{j<i} bu[j][d]
        const int idx = b - 160;        // 0..31
        const int i = idx >> 2, d = (idx & 3) * 256 + t;
        double s = 0.0;
        for (int j = 0; j < i; ++j) s += (double)bu[j * 1024 + d];
        sbu[i * 1024 + d] = s;
    } else {
        if (t == 0) wacc[0] = 0.0;
    }
}

// ============================ prep2 ============================
// blocks [0,64): G pair (j=b>>3, i=b&7, skip j>=i) | [64,72): hv row i=b-64
__global__ void __launch_bounds__(256) rvq_prep2(
    const float* __restrict__ Wu, const float* __restrict__ Wd,
    const float* __restrict__ bd, const double* __restrict__ sbu,
    double* __restrict__ G64, float* __restrict__ G32,
    double* __restrict__ hv64, float* __restrict__ hv32)
{
    __shared__ double sm2[1200];
    float* smf = (float*)sm2;
    const int b = blockIdx.x, t = threadIdx.x;
    if (b < 64) {
        const int j = b >> 3, i = b & 7;
        if (j >= i) return;
        float* Aus = smf;               // [64][20] Wu[j, d, a]
        float* Bds = smf + 1280;        // [16][68] Wd[i, b, d]
        const int a = t >> 4, bb = t & 15;
        double s = 0.0;
        for (int ch = 0; ch < 16; ++ch) {
            __syncthreads();
            {
                const int dd = t >> 2, a4 = (t & 3) * 4;
                const float4 v = *(const float4*)(Wu + (size_t)j * 16384
                                  + (size_t)(ch * 64 + dd) * 16 + a4);
                *(float4*)&Aus[dd * 20 + a4] = v;
                const int br = t >> 4, d4 = (t & 15) * 4;
                const float4 w = *(const float4*)(Wd + (size_t)i * 16384
                                  + (size_t)br * 1024 + ch * 64 + d4);
                *(float4*)&Bds[br * 68 + d4] = w;
            }
            __syncthreads();
#pragma unroll
            for (int dd = 0; dd < 64; ++dd)
                s = fma((double)Aus[dd * 20 + a], (double)Bds[bb * 68 + dd], s);
        }
        G64[(size_t)(j * 8 + i) * 256 + t] = s;
        G32[(size_t)(j * 8 + i) * 256 + t] = (float)s;
    } else {
        const int i = b - 64;
        const int dq = t >> 4, bb = t & 15;
        const double* sp = sbu + i * 1024 + dq * 64;
        const float*  wp = Wd + (size_t)i * 16384 + (size_t)bb * 1024 + dq * 64;
        double s = 0.0;
#pragma unroll
        for (int dd = 0; dd < 64; ++dd)
            s = fma(sp[dd], (double)wp[dd], s);
        sm2[dq * 20 + bb] = s;
        __syncthreads();
        if (t < 16) {
            double s2 = 0.0;
#pragma unroll
            for (int q = 0; q < 16; ++q) s2 += sm2[q * 20 + t];
            const double h = (double)bd[i * 16 + t] - s2;
            hv64[i * 16 + t] = h; hv32[i * 16 + t] = (float)h;
        }
    }
}

// ============================ main ============================
// 1024 blocks x 256 threads, 32 tokens/block, ~34KB LDS -> 4 blocks/CU
// (exactly full residency: 1024 = 4 x 256 CUs).
__global__ void __launch_bounds__(256, 4) rvq_main(
    const float* __restrict__ z_e, const float* __restrict__ Wd,
    const float* __restrict__ cb,
    const float* __restrict__ Bmat, const float* __restrict__ hv32,
    const double* __restrict__ hv64,
    const float* __restrict__ cbn32, const double* __restrict__ cbn64,
    const float* __restrict__ G32, const double* __restrict__ G64,
    double* __restrict__ wacc,
    float* __restrict__ out0, float* __restrict__ out1)
{
    __shared__ __attribute__((aligned(16))) double stag_d[1312]; // 10.25KB union:
                                        // GEMM tiles (2624 f) / recheck (672 d) / G32 (1792 f)
    __shared__ float ybuf[32 * 132];    // 16.9KB
    __shared__ float znbuf[32 * 20];
    __shared__ float candd[128], candd2[128];
    __shared__ int   candk[128];
    __shared__ float zqs[32 * 17];
    __shared__ int   bkhist[256];
    __shared__ int   bks[32], flist[32];
    __shared__ int   flagcnt;
    float* stag = reinterpret_cast<float*>(stag_d);

    const int t = threadIdx.x;
    const int tok0g = blockIdx.x * 32;

    // ---------------- GEMM: y = z_e . Bmat + hv ----------------
    // acc[4 tok][4 col]: per kk 1 b128 A-read (32-lane bcast) + 1 b128 B-read
    // per 16 FMA. B staged async via global_load_lds (linear stride-128 tile).
    {
        float* As = stag;               // [16][36]  transposed z_e slice
        float* Bs = stag + 576;         // [16][128] linear (matches Bmat rows)
        const int tg2 = t >> 5, cg2 = t & 31;
        const int wid = t >> 6, lane = t & 63;
        float acc[4][4];
#pragma unroll
        for (int h = 0; h < 4; ++h)
#pragma unroll
            for (int x = 0; x < 4; ++x) acc[h][x] = 0.f;

#pragma unroll 1
        for (int ko = 0; ko < 64; ++ko) {
            const int k0 = ko * 16;
            __syncthreads();
            {   // A: 32 tok x 16 k, transposed via regs (conflict-free writes)
                const int m = t >> 3, kk2 = (t & 7) * 2;
                const float2 v = *(const float2*)(z_e +
                    (size_t)(tok0g + m) * 1024 + k0 + kk2);
                As[kk2 * 36 + m] = v.x;
                As[(kk2 + 1) * 36 + m] = v.y;
            }
            {   // B: 16 k x 128 n, async global->LDS (2 x 1KB per wave)
                const float* bsrc = Bmat + (size_t)k0 * 128 + wid * 512 + lane * 4;
                float* bdst = Bs + wid * 512;
                gload_lds16(bsrc, bdst);
                gload_lds16(bsrc + 256, bdst + 256);
            }
            __syncthreads();            // drains vmcnt (gload_lds) + lgkm (As)
#pragma unroll
            for (int kk = 0; kk < 16; ++kk) {
                const float4 a4 = *(const float4*)&As[kk * 36 + tg2 * 4];
                const float4 b4 = *(const float4*)&Bs[kk * 128 + cg2 * 4];
                acc[0][0] = fmaf(a4.x, b4.x, acc[0][0]);
                acc[0][1] = fmaf(a4.x, b4.y, acc[0][1]);
                acc[0][2] = fmaf(a4.x, b4.z, acc[0][2]);
                acc[0][3] = fmaf(a4.x, b4.w, acc[0][3]);
                acc[1][0] = fmaf(a4.y, b4.x, acc[1][0]);
                acc[1][1] = fmaf(a4.y, b4.y, acc[1][1]);
                acc[1][2] = fmaf(a4.y, b4.z, acc[1][2]);
                acc[1][3] = fmaf(a4.y, b4.w, acc[1][3]);
                acc[2][0] = fmaf(a4.z, b4.x, acc[2][0]);
                acc[2][1] = fmaf(a4.z, b4.y, acc[2][1]);
                acc[2][2] = fmaf(a4.z, b4.z, acc[2][2]);
                acc[2][3] = fmaf(a4.z, b4.w, acc[2][3]);
                acc[3][0] = fmaf(a4.w, b4.x, acc[3][0]);
                acc[3][1] = fmaf(a4.w, b4.y, acc[3][1]);
                acc[3][2] = fmaf(a4.w, b4.z, acc[3][2]);
                acc[3][3] = fmaf(a4.w, b4.w, acc[3][3]);
            }
        }
        const float4 hv = *(const float4*)(hv32 + cg2 * 4);
#pragma unroll
        for (int h = 0; h < 4; ++h) {
            float4 y4;
            y4.x = acc[h][0] + hv.x;
            y4.y = acc[h][1] + hv.y;
            y4.z = acc[h][2] + hv.z;
            y4.w = acc[h][3] + hv.w;
            *(float4*)&ybuf[(tg2 * 4 + h) * 132 + cg2 * 4] = y4;
        }
    }

    // ---------------- layer loop ----------------
    double lacc = 0.0;
    const int cg = t >> 3, tg = t & 7; // 32 code-groups x 8 token-groups(4 tok)
#pragma unroll 1
    for (int l = 0; l < 8; ++l) {
        __syncthreads();                // ybuf (GEMM epilogue / prev corrections)
        if (t < 32) {                   // normalize token t once into LDS
            const float* yr = &ybuf[t * 132 + l * 16];
            float yv[16]; float n2 = 0.f;
#pragma unroll
            for (int c = 0; c < 16; ++c) { yv[c] = yr[c]; n2 = fmaf(yv[c], yv[c], n2); }
            const float iv = 1.0f / fmaxf(sqrtf(n2), 1e-12f);
            float* zp = &znbuf[t * 20];
#pragma unroll
            for (int c = 0; c < 16; ++c) zp[c] = yv[c] * iv;
        }
        __syncthreads();

        // tokens tg+8h into registers (adjacent-row reads: conflict-free)
        float zn[4][16];
#pragma unroll
        for (int h = 0; h < 4; ++h) {
            const float* zp = &znbuf[(tg + 8 * h) * 20];
            const float4 z0 = *(const float4*)(zp);
            const float4 z1 = *(const float4*)(zp + 4);
            const float4 z2 = *(const float4*)(zp + 8);
            const float4 z3 = *(const float4*)(zp + 12);
            zn[h][0] = z0.x; zn[h][1] = z0.y; zn[h][2]  = z0.z; zn[h][3]  = z0.w;
            zn[h][4] = z1.x; zn[h][5] = z1.y; zn[h][6]  = z1.z; zn[h][7]  = z1.w;
            zn[h][8] = z2.x; zn[h][9] = z2.y; zn[h][10] = z2.z; zn[h][11] = z2.w;
            zn[h][12] = z3.x; zn[h][13] = z3.y; zn[h][14] = z3.z; zn[h][15] = z3.w;
        }

        // ---- distance scan: codebook rows direct from L2, no LDS, no syncs ----
        float bs[4], bs2[4]; int bk[4];
#pragma unroll
        for (int h = 0; h < 4; ++h) { bs[h] = 1e30f; bs2[h] = 1e30f; bk[h] = -1; }
        const float* cb_l = cbn32 + (size_t)l * 1024 * 20;
#pragma unroll 2
        for (int kk = 0; kk < 32; ++kk) {
            const int k = (kk << 5) + cg;           // monotone per thread
            const float* rp = cb_l + (size_t)k * 20;
            const float4 c0 = *(const float4*)(rp);
            const float4 c1 = *(const float4*)(rp + 4);
            const float4 c2 = *(const float4*)(rp + 8);
            const float4 c3 = *(const float4*)(rp + 12);
            const float cn2 = rp[16];
#pragma unroll
            for (int h = 0; h < 4; ++h) {
                float d;
                d = c0.x * zn[h][0];
                d = fmaf(c0.y, zn[h][1], d);
                d = fmaf(c0.z, zn[h][2], d);
                d = fmaf(c0.w, zn[h][3], d);
                d = fmaf(c1.x, zn[h][4], d);
                d = fmaf(c1.y, zn[h][5], d);
                d = fmaf(c1.z, zn[h][6], d);
                d = fmaf(c1.w, zn[h][7], d);
                d = fmaf(c2.x, zn[h][8], d);
                d = fmaf(c2.y, zn[h][9], d);
                d = fmaf(c2.z, zn[h][10], d);
                d = fmaf(c2.w, zn[h][11], d);
                d = fmaf(c3.x, zn[h][12], d);
                d = fmaf(c3.y, zn[h][13], d);
                d = fmaf(c3.z, zn[h][14], d);
                d = fmaf(c3.w, zn[h][15], d);
                const float s = fmaf(-2.f, d, cn2);
                const bool w = s < bs[h];
                bs2[h] = w ? bs[h] : fminf(bs2[h], s);
                bk[h]  = w ? k : bk[h];
                bs[h]  = w ? s : bs[h];
            }
        }

        // ---- wave-level lexicographic top-2 merge over the 8 cg's sharing tokens
#pragma unroll
        for (int m = 8; m <= 32; m <<= 1) {
#pragma unroll
            for (int h = 0; h < 4; ++h) {
                const float ob = __shfl_xor(bs[h], m);
                const float os = __shfl_xor(bs2[h], m);
                const int   ok = __shfl_xor(bk[h], m);
                const bool w = (ob < bs[h]) || (ob == bs[h] && ok < bk[h]);
                const float loser = w ? bs[h] : ob;
                bs2[h] = fminf(fminf(bs2[h], os), loser);
                bs[h]  = w ? ob : bs[h];
                bk[h]  = w ? ok : bk[h];
            }
        }
        if (t == 0) flagcnt = 0;
        if ((t & 63) < 8) {             // one writer per token per wave
            const int base = (t >> 6) * 32 + tg;
#pragma unroll
            for (int h = 0; h < 4; ++h) {
                candd [base + 8 * h] = bs[h];
                candd2[base + 8 * h] = bs2[h];
                candk [base + 8 * h] = bk[h];
            }
        }
        __syncthreads();
        if (t < 32) {                   // final merge over 4 waves
            float best = 1e30f, sec = 1e30f; int bkk = -1;
#pragma unroll
            for (int c = 0; c < 4; ++c) {
                const float d  = candd [c * 32 + t];
                const float d2 = candd2[c * 32 + t];
                const int   k  = candk [c * 32 + t];
                const bool w = (d < best) || (d == best && k < bkk);
                const float nw = fminf(sec, fminf(best, d2));
                const float nl = fminf(sec, d);
                sec  = w ? nw : nl;
                bkk  = w ? k : bkk;
                best = w ? d : best;
            }
            bks[t] = bkk;
            const float* yr = &ybuf[t * 132 + l * 16];
            float n2 = 0.f;
#pragma unroll
            for (int c = 0; c < 16; ++c) n2 = fmaf(yr[c], yr[c], n2);
            if ((sec - best < TAU) || (n2 < 1e-3f)) {
                const int p = atomicAdd(&flagcnt, 1); flist[p] = t;
            }
        }
        __syncthreads();

        // ---- rare fp64 recheck (exact reference argmin) ----
        const int nf = flagcnt;
#pragma unroll 1
        for (int f = 0; f < nf; ++f) {
            const int tok = flist[f];
            double* rpd = stag_d;
            {
                const int c = t & 15, ch = t >> 4;
                const float* gz = z_e + (size_t)(tok0g + tok) * 1024 + ch * 64;
                const float* wp = Wd + ((size_t)l * 16 + c) * 1024 + ch * 64;
                double pd = 0.0;
                for (int dd = 0; dd < 64; ++dd)
                    pd = fma((double)gz[dd], (double)wp[dd], pd);
                rpd[c * 16 + ch] = pd;
            }
            __syncthreads();
            if (t < 16) {
                double y = hv64[l * 16 + t];
#pragma unroll
                for (int ch = 0; ch < 16; ++ch) y += rpd[t * 16 + ch];
                for (int j = 0; j < l; ++j) {
                    const int bkj = bkhist[tok * 8 + j];
                    const float* qv = cb + ((size_t)j * 1024 + bkj) * 16;
                    const double* gp = G64 + (size_t)(j * 8 + l) * 256 + t;
                    double s = 0.0;
#pragma unroll
                    for (int a = 0; a < 16; ++a)
                        s = fma((double)qv[a], gp[a * 16], s);
                    y -= s;
                }
                rpd[256 + t] = y;
            }
            __syncthreads();
            if (t == 0) {
                double n2 = 0.0;
#pragma unroll
                for (int c = 0; c < 16; ++c) n2 = fma(rpd[256 + c], rpd[256 + c], n2);
                const double iv = 1.0 / fmax(sqrt(n2), 1e-12);
#pragma unroll
                for (int c = 0; c < 16; ++c) rpd[272 + c] = rpd[256 + c] * iv;
            }
            __syncthreads();
            {
                double bd_ = 1e300; int bk_ = -1;
#pragma unroll
                for (int q = 0; q < 4; ++q) {
                    const int k = q * 256 + t;
                    const double* row = cbn64 + (size_t)(l * 1024 + k) * 17;
                    double dot = 0.0;
#pragma unroll
                    for (int c = 0; c < 16; ++c) dot = fma(row[c], rpd[272 + c], dot);
                    const double s = fma(-2.0, dot, row[16]);
                    if (s < bd_) { bd_ = s; bk_ = k; }
                }
                rpd[288 + t] = bd_;
                ((int*)&rpd[544])[t] = bk_;
            }
            __syncthreads();
            if (t == 0) {
                double bd_ = 1e300; int bk_ = -1;
                for (int i = 0; i < 256; ++i) {
                    const double d = rpd[288 + i];
                    const int k = ((int*)&rpd[544])[i];
                    if (d < bd_ || (d == bd_ && k < bk_)) { bd_ = d; bk_ = k; }
                }
                bks[tok] = bk_;
            }
            __syncthreads();
        }

        // ---- outputs, loss ----
        if (t < 32) {
            const int bk_ = bks[t];
            bkhist[t * 8 + l] = bk_;
            const float4* qp = (const float4*)(cb + ((size_t)l * 1024 + bk_) * 16);
            const float4 q0 = qp[0], q1 = qp[1], q2 = qp[2], q3 = qp[3];
            float* op = out0 + (size_t)(tok0g + t) * 128 + l * 16;
            ((float4*)op)[0] = q0; ((float4*)op)[1] = q1;
            ((float4*)op)[2] = q2; ((float4*)op)[3] = q3;
            out1[(size_t)(tok0g + t) * 8 + l] = (float)bk_;
            const float qf[16] = {q0.x,q0.y,q0.z,q0.w, q1.x,q1.y,q1.z,q1.w,
                                  q2.x,q2.y,q2.z,q2.w, q3.x,q3.y,q3.z,q3.w};
#pragma unroll
            for (int a = 0; a < 16; ++a) zqs[t * 17 + a] = qf[a];
            const float* yr = &ybuf[t * 132 + l * 16];
#pragma unroll
            for (int c = 0; c < 16; ++c) {
                const float d = yr[c] - qf[c];
                lacc += (double)d * (double)d;
            }
        }
        __syncthreads();

        // ---- corrections: ybuf[tok][ii*16+b] -= sum_a zq[a]*G32[l][ii][a][b] ----
        if (l < 7) {
            {
                const int total = (7 - l) * 256;
                for (int idx = t; idx < total; idx += 256) {
                    const int ii = l + 1 + (idx >> 8);
                    stag[idx] = G32[(size_t)(l * 8 + ii) * 256 + (idx & 255)];
                }
            }
            __syncthreads();
            const int part = t >> 5, tok = t & 31;
            const int ii = l + 1 + part;
            if (ii < 8) {
                float zql[16];
#pragma unroll
                for (int a = 0; a < 16; ++a) zql[a] = zqs[tok * 17 + a];
                const float* gb = &stag[part * 256];
                float corr[16];
#pragma unroll
                for (int x = 0; x < 16; ++x) corr[x] = 0.f;
#pragma unroll
                for (int a = 0; a < 16; ++a) {
                    const float4 g0 = *(const float4*)&gb[a * 16];
                    const float4 g1 = *(const float4*)&gb[a * 16 + 4];
                    const float4 g2 = *(const float4*)&gb[a * 16 + 8];
                    const float4 g3 = *(const float4*)&gb[a * 16 + 12];
                    const float za = zql[a];
                    corr[0]  = fmaf(za, g0.x, corr[0]);  corr[1]  = fmaf(za, g0.y, corr[1]);
                    corr[2]  = fmaf(za, g0.z, corr[2]);  corr[3]  = fmaf(za, g0.w, corr[3]);
                    corr[4]  = fmaf(za, g1.x, corr[4]);  corr[5]  = fmaf(za, g1.y, corr[5]);
                    corr[6]  = fmaf(za, g1.z, corr[6]);  corr[7]  = fmaf(za, g1.w, corr[7]);
                    corr[8]  = fmaf(za, g2.x, corr[8]);  corr[9]  = fmaf(za, g2.y, corr[9]);
                    corr[10] = fmaf(za, g2.z, corr[10]); corr[11] = fmaf(za, g2.w, corr[11]);
                    corr[12] = fmaf(za, g3.x, corr[12]); corr[13] = fmaf(za, g3.y, corr[13]);
                    corr[14] = fmaf(za, g3.z, corr[14]); corr[15] = fmaf(za, g3.w, corr[15]);
                }
                float* yr = &ybuf[tok * 132 + ii * 16];
#pragma unroll
                for (int v = 0; v < 4; ++v) {
                    float4 y4 = *(float4*)&yr[v * 4];
                    y4.x -= corr[v * 4 + 0]; y4.y -= corr[v * 4 + 1];
                    y4.z -= corr[v * 4 + 2]; y4.w -= corr[v * 4 + 3];
                    *(float4*)&yr[v * 4] = y4;
                }
            }
        }
    }

    if (t < 64) {
#pragma unroll
        for (int off = 32; off > 0; off >>= 1) lacc += __shfl_down(lacc, off);
        if (t == 0) atomicAdd(wacc, lacc);
    }
}

__global__ void __launch_bounds__(64) rvq_fin(const double* __restrict__ wacc,
                                              float* __restrict__ lossp) {
    if (threadIdx.x == 0) {
        const float v = (float)(wacc[0] * (1.0 / 524288.0));
        lossp[0] = v; lossp[1] = v; lossp[2] = 0.0f;
    }
}

extern "C" void kernel_launch(void* const* d_in, const int* in_sizes, int n_in,
                              void* d_out, int out_size, void* d_ws, size_t ws_size,
                              hipStream_t stream) {
    (void)in_sizes; (void)n_in; (void)ws_size;
    const float* z_e = (const float*)d_in[0];
    const float* Wd  = (const float*)d_in[1];
    const float* bd  = (const float*)d_in[2];
    const float* cb  = (const float*)d_in[3];
    const float* Wu  = (const float*)d_in[4];
    const float* bu  = (const float*)d_in[5];

    float* out0  = (float*)d_out;                      // (8,4096,128)
    float* out1  = out0 + (size_t)8 * 4096 * 128;      // (8,4096,8) codes
    float* lossp = out0 + (size_t)out_size - 3;        // commit, cbl, entropy

    char* ws = (char*)d_ws;
    double* wacc  = (double*)(ws + WS_WACC);
    double* hv64  = (double*)(ws + WS_HV64);
    double* G64   = (double*)(ws + WS_G64);
    double* cbn64 = (double*)(ws + WS_CBN64);
    float*  cbn32 = (float*) (ws + WS_CBN32);
    float*  G32   = (float*) (ws + WS_G32);
    float*  hv32  = (float*) (ws + WS_HV32);
    float*  Bmat  = (float*) (ws + WS_BMAT);
    double* sbu   = (double*)(ws + WS_SBU);

    rvq_prep1<<<193, 256, 0, stream>>>(cb, Wd, bu, cbn64, cbn32, Bmat, sbu, wacc);
    rvq_prep2<<<72, 256, 0, stream>>>(Wu, Wd, bd, sbu, G64, G32, hv64, hv32);
    rvq_main<<<1024, 256, 0, stream>>>(z_e, Wd, cb, Bmat, hv32, hv64,
                                       cbn32, cbn64, G32, G64, wacc, out0, out1);
    rvq_fin<<<1, 64, 0, stream>>>(wacc, lossp);
}

// Round 2
// 658.250 us; speedup vs baseline: 1.3119x; 1.0408x over previous
//
#include <hip/hip_runtime.h>
#include <math.h>

// ResidualVQ fused forward, MI355X (gfx950) — round 6.
// R5 post-mortem: 558us, VALUBusy 36.7%, MfmaUtil 0, HBM 8% -> the distance
// scan (32x1024x16 matmul per block-layer) runs on the VALU (~160us VALU +
// stalls). R6: distance scan on MFMA (bf16 hi/lo split, 2x mfma 16x16x32 per
// tile; error <= 2.4e-5 << TAU so fp64-recheck guard keeps selection exact);
// cn2 dropped (unit-norm codes, |cn2-1|<=5e-7 << TAU, covered by guard);
// codebook stored as prebuilt bf16 frag rows (512KB, reuses cbn32 slot).
// GEMM / normalize / recheck / outputs / corrections unchanged from R5.

#define TAU 3e-4f

// ws byte offsets
#define WS_WACC   0
#define WS_HV64   64
#define WS_G64    2048
#define WS_CBN64  133120
#define WS_CBF    1247232   // 8192 codes x 32 ushort (bf16 hi|lo) = 512KB
#define WS_G32    1902592
#define WS_HV32   1968128
#define WS_BMAT   1968640
#define WS_SBU    2492928

typedef __attribute__((ext_vector_type(8))) short short8v;
typedef __attribute__((ext_vector_type(4))) float f32x4;

__device__ __forceinline__ void gload_lds16(const void* g, void* l) {
    __builtin_amdgcn_global_load_lds(
        (const __attribute__((address_space(1))) void*)g,
        (__attribute__((address_space(3))) void*)l, 16, 0, 0);
}

__device__ __forceinline__ unsigned short bf16_rne(float x) {
    unsigned u = __float_as_uint(x);
    u += 0x7FFFu + ((u >> 16) & 1u);
    return (unsigned short)(u >> 16);
}
__device__ __forceinline__ float bf16_to_f32(unsigned short h) {
    return __uint_as_float(((unsigned)h) << 16);
}

// ============================ prep1 ============================
// blocks: [0,32) cbn64+cbf | [32,160) bmat | [160,192) sbu | 192 zero
__global__ void __launch_bounds__(256) rvq_prep1(
    const float* __restrict__ cb, const float* __restrict__ Wd,
    const float* __restrict__ bu,
    double* __restrict__ cbn64, unsigned short* __restrict__ cbf,
    float* __restrict__ Bmat, double* __restrict__ sbu,
    double* __restrict__ wacc)
{
    const int b = blockIdx.x, t = threadIdx.x;
    if (b < 32) {                       // normalized codebook fp64 + bf16 hi/lo
        const int idx = b * 256 + t;    // l*1024+k
        const float* cp = cb + (size_t)idx * 16;
        double v[16]; double n = 0.0;
#pragma unroll
        for (int c = 0; c < 16; ++c) { v[c] = (double)cp[c]; n = fma(v[c], v[c], n); }
        const double iv = 1.0 / fmax(sqrt(n), 1e-12);
        double* r64 = cbn64 + (size_t)idx * 17;
        unsigned short* cf = cbf + (size_t)idx * 32;
        double c2 = 0.0;
#pragma unroll
        for (int c = 0; c < 16; ++c) {
            const double x = v[c] * iv;
            c2 = fma(x, x, c2);
            r64[c] = x;
            const float xf = (float)x;
            const unsigned short hh = bf16_rne(xf);
            cf[c] = hh;
            cf[16 + c] = bf16_rne(xf - bf16_to_f32(hh));
        }
        r64[16] = c2;
    } else if (b < 160) {               // Bmat[d][ic] = Wd[ic][d]
        const int ic = b - 32;
        const int d0 = t * 4;
        const float4 v = *(const float4*)(Wd + (size_t)ic * 1024 + d0);
        Bmat[(size_t)(d0 + 0) * 128 + ic] = v.x;
        Bmat[(size_t)(d0 + 1) * 128 + ic] = v.y;
        Bmat[(size_t)(d0 + 2) * 128 + ic] = v.z;
        Bmat[(size_t)(d0 + 3) * 128 + ic] = v.w;
    } else if (b < 192) {               // sbu[i][d] = sum_{j<i} bu[j][d]
        const int idx = b - 160;        // 0..31
        const int i = idx >> 2, d = (idx & 3) * 256 + t;
        double s = 0.0;
        for (int j = 0; j < i; ++j) s += (double)bu[j * 1024 + d];
        sbu[i * 1024 + d] = s;
    } else {
        if (t == 0) wacc[0] = 0.0;
    }
}

// ============================ prep2 ============================
// blocks [0,64): G pair (j=b>>3, i=b&7, skip j>=i) | [64,72): hv row i=b-64
__global__ void __launch_bounds__(256) rvq_prep2(
    const float* __restrict__ Wu, const float* __restrict__ Wd,
    const float* __restrict__ bd, const double* __restrict__ sbu,
    double* __restrict__ G64, float* __restrict__ G32,
    double* __restrict__ hv64, float* __restrict__ hv32)
{
    __shared__ double sm2[1200];
    float* smf = (float*)sm2;
    const int b = blockIdx.x, t = threadIdx.x;
    if (b < 64) {
        const int j = b >> 3, i = b & 7;
        if (j >= i) return;
        float* Aus = smf;               // [64][20] Wu[j, d, a]
        float* Bds = smf + 1280;        // [16][68] Wd[i, b, d]
        const int a = t >> 4, bb = t & 15;
        double s = 0.0;
        for (int ch = 0; ch < 16; ++ch) {
            __syncthreads();
            {
                const int dd = t >> 2, a4 = (t & 3) * 4;
                const float4 v = *(const float4*)(Wu + (size_t)j * 16384
                                  + (size_t)(ch * 64 + dd) * 16 + a4);
                *(float4*)&Aus[dd * 20 + a4] = v;
                const int br = t >> 4, d4 = (t & 15) * 4;
                const float4 w = *(const float4*)(Wd + (size_t)i * 16384
                                  + (size_t)br * 1024 + ch * 64 + d4);
                *(float4*)&Bds[br * 68 + d4] = w;
            }
            __syncthreads();
#pragma unroll
            for (int dd = 0; dd < 64; ++dd)
                s = fma((double)Aus[dd * 20 + a], (double)Bds[bb * 68 + dd], s);
        }
        G64[(size_t)(j * 8 + i) * 256 + t] = s;
        G32[(size_t)(j * 8 + i) * 256 + t] = (float)s;
    } else {
        const int i = b - 64;
        const int dq = t >> 4, bb = t & 15;
        const double* sp = sbu + i * 1024 + dq * 64;
        const float*  wp = Wd + (size_t)i * 16384 + (size_t)bb * 1024 + dq * 64;
        double s = 0.0;
#pragma unroll
        for (int dd = 0; dd < 64; ++dd)
            s = fma(sp[dd], (double)wp[dd], s);
        sm2[dq * 20 + bb] = s;
        __syncthreads();
        if (t < 16) {
            double s2 = 0.0;
#pragma unroll
            for (int q = 0; q < 16; ++q) s2 += sm2[q * 20 + t];
            const double h = (double)bd[i * 16 + t] - s2;
            hv64[i * 16 + t] = h; hv32[i * 16 + t] = (float)h;
        }
    }
}

// ============================ main ============================
// 1024 blocks x 256 threads, 32 tokens/block, ~34KB LDS -> 4 blocks/CU.
__global__ void __launch_bounds__(256, 4) rvq_main(
    const float* __restrict__ z_e, const float* __restrict__ Wd,
    const float* __restrict__ cb,
    const float* __restrict__ Bmat, const float* __restrict__ hv32,
    const double* __restrict__ hv64,
    const unsigned short* __restrict__ cbf, const double* __restrict__ cbn64,
    const float* __restrict__ G32, const double* __restrict__ G64,
    double* __restrict__ wacc,
    float* __restrict__ out0, float* __restrict__ out1)
{
    __shared__ __attribute__((aligned(16))) double stag_d[1312]; // 10.25KB union:
                                        // GEMM tiles (2624 f) / recheck (672 d) / G32 (1792 f)
    __shared__ float ybuf[32 * 132];    // 16.9KB
    __shared__ float znbuf[32 * 20];
    __shared__ float candd[64], candd2[64];
    __shared__ int   candk[64];
    __shared__ float zqs[32 * 17];
    __shared__ int   bkhist[256];
    __shared__ int   bks[32], flist[32];
    __shared__ int   flagcnt;
    float* stag = reinterpret_cast<float*>(stag_d);

    const int t = threadIdx.x;
    const int tok0g = blockIdx.x * 32;

    // ---------------- GEMM: y = z_e . Bmat + hv ---------------- (as R5)
    {
        float* As = stag;               // [16][36]  transposed z_e slice
        float* Bs = stag + 576;         // [16][128] linear (matches Bmat rows)
        const int tg2 = t >> 5, cg2 = t & 31;
        const int wid = t >> 6, lane = t & 63;
        float acc[4][4];
#pragma unroll
        for (int h = 0; h < 4; ++h)
#pragma unroll
            for (int x = 0; x < 4; ++x) acc[h][x] = 0.f;

#pragma unroll 1
        for (int ko = 0; ko < 64; ++ko) {
            const int k0 = ko * 16;
            __syncthreads();
            {   // A: 32 tok x 16 k, transposed via regs (conflict-free writes)
                const int m = t >> 3, kk2 = (t & 7) * 2;
                const float2 v = *(const float2*)(z_e +
                    (size_t)(tok0g + m) * 1024 + k0 + kk2);
                As[kk2 * 36 + m] = v.x;
                As[(kk2 + 1) * 36 + m] = v.y;
            }
            {   // B: 16 k x 128 n, async global->LDS (2 x 1KB per wave)
                const float* bsrc = Bmat + (size_t)k0 * 128 + wid * 512 + lane * 4;
                float* bdst = Bs + wid * 512;
                gload_lds16(bsrc, bdst);
                gload_lds16(bsrc + 256, bdst + 256);
            }
            __syncthreads();            // drains vmcnt (gload_lds) + lgkm (As)
#pragma unroll
            for (int kk = 0; kk < 16; ++kk) {
                const float4 a4 = *(const float4*)&As[kk * 36 + tg2 * 4];
                const float4 b4 = *(const float4*)&Bs[kk * 128 + cg2 * 4];
                acc[0][0] = fmaf(a4.x, b4.x, acc[0][0]);
                acc[0][1] = fmaf(a4.x, b4.y, acc[0][1]);
                acc[0][2] = fmaf(a4.x, b4.z, acc[0][2]);
                acc[0][3] = fmaf(a4.x, b4.w, acc[0][3]);
                acc[1][0] = fmaf(a4.y, b4.x, acc[1][0]);
                acc[1][1] = fmaf(a4.y, b4.y, acc[1][1]);
                acc[1][2] = fmaf(a4.y, b4.z, acc[1][2]);
                acc[1][3] = fmaf(a4.y, b4.w, acc[1][3]);
                acc[2][0] = fmaf(a4.z, b4.x, acc[2][0]);
                acc[2][1] = fmaf(a4.z, b4.y, acc[2][1]);
                acc[2][2] = fmaf(a4.z, b4.z, acc[2][2]);
                acc[2][3] = fmaf(a4.z, b4.w, acc[2][3]);
                acc[3][0] = fmaf(a4.w, b4.x, acc[3][0]);
                acc[3][1] = fmaf(a4.w, b4.y, acc[3][1]);
                acc[3][2] = fmaf(a4.w, b4.z, acc[3][2]);
                acc[3][3] = fmaf(a4.w, b4.w, acc[3][3]);
            }
        }
        const float4 hv = *(const float4*)(hv32 + cg2 * 4);
#pragma unroll
        for (int h = 0; h < 4; ++h) {
            float4 y4;
            y4.x = acc[h][0] + hv.x;
            y4.y = acc[h][1] + hv.y;
            y4.z = acc[h][2] + hv.z;
            y4.w = acc[h][3] + hv.w;
            *(float4*)&ybuf[(tg2 * 4 + h) * 132 + cg2 * 4] = y4;
        }
    }

    // ---------------- layer loop ----------------
    double lacc = 0.0;
    const int w = t >> 6, lane = t & 63;
    const int blk = lane >> 4, col = lane & 15;
    const int Tt = w & 1, Hh = w >> 1;      // token-tile / code-half per wave
    const bool lolane = blk >= 2;
#pragma unroll 1
    for (int l = 0; l < 8; ++l) {
        __syncthreads();                // ybuf (GEMM epilogue / prev corrections)
        if (t < 32) {                   // normalize token t once into LDS
            const float* yr = &ybuf[t * 132 + l * 16];
            float yv[16]; float n2 = 0.f;
#pragma unroll
            for (int c = 0; c < 16; ++c) { yv[c] = yr[c]; n2 = fmaf(yv[c], yv[c], n2); }
            const float iv = 1.0f / fmaxf(sqrtf(n2), 1e-12f);
            float* zp = &znbuf[t * 20];
#pragma unroll
            for (int c = 0; c < 16; ++c) zp[c] = yv[c] * iv;
        }
        __syncthreads();

        // ---- A fragment: A[row=token][k], k<16: bf16hi(-2*zn), k>=16: bf16lo ----
        // lane layout (mfma_f32_16x16x32_bf16): row=lane&15, k=(lane>>4)*8+i.
        short8v afrag;
        {
            const float* zp = &znbuf[(Tt * 16 + col) * 20 + (blk & 1) * 8];
            const float4 z0 = *(const float4*)zp;
            const float4 z1 = *(const float4*)(zp + 4);
            const float zv[8] = {z0.x, z0.y, z0.z, z0.w, z1.x, z1.y, z1.z, z1.w};
#pragma unroll
            for (int i = 0; i < 8; ++i) {
                const float x = -2.f * zv[i];
                const unsigned short h = bf16_rne(x);
                const unsigned short v2 = lolane ? bf16_rne(x - bf16_to_f32(h)) : h;
                afrag[i] = (short)v2;
            }
        }

        // ---- distance scan: 2 MFMA per 16x16 tile; s = -2*dot (cn2==1 folded
        //      into the TAU guard). B1=[ch;ch], B2=[cl;0]. ----
        float bs[4], bs2[4]; int bk[4];
#pragma unroll
        for (int r = 0; r < 4; ++r) { bs[r] = 1e30f; bs2[r] = 1e30f; bk[r] = -1; }
        const unsigned short* cbp = cbf + ((size_t)(l * 1024 + Hh * 512 + col)) * 32;
        const unsigned short* p1 = cbp + (blk & 1) * 8;        // ch half
        const unsigned short* p2 = cbp + 16 + (blk & 1) * 8;   // cl half (blk<2)
#pragma unroll 2
        for (int tile = 0; tile < 32; ++tile) {
            const short8v b1 = *(const short8v*)(p1 + tile * 512);
            short8v b2 = {};
            if (!lolane) b2 = *(const short8v*)(p2 + tile * 512);
            f32x4 acc = {0.f, 0.f, 0.f, 0.f};
            acc = __builtin_amdgcn_mfma_f32_16x16x32_bf16(afrag, b1, acc, 0, 0, 0);
            acc = __builtin_amdgcn_mfma_f32_16x16x32_bf16(afrag, b2, acc, 0, 0, 0);
            const int k = Hh * 512 + tile * 16 + col;
#pragma unroll
            for (int r = 0; r < 4; ++r) {
                const float s = acc[r];
                const bool wn = s < bs[r];
                bs2[r] = wn ? bs[r] : fminf(bs2[r], s);
                bk[r]  = wn ? k : bk[r];
                bs[r]  = wn ? s : bs[r];
            }
        }

        // ---- lexicographic top-2 merge across the 16 cols (within blk-group) ----
#pragma unroll
        for (int m = 1; m <= 8; m <<= 1) {
#pragma unroll
            for (int r = 0; r < 4; ++r) {
                const float ob = __shfl_xor(bs[r], m);
                const float os = __shfl_xor(bs2[r], m);
                const int   ok = __shfl_xor(bk[r], m);
                const bool wn = (ob < bs[r]) || (ob == bs[r] && ok < bk[r]);
                const float loser = wn ? bs[r] : ob;
                bs2[r] = fminf(fminf(bs2[r], os), loser);
                bs[r]  = wn ? ob : bs[r];
                bk[r]  = wn ? ok : bk[r];
            }
        }
        if (t == 0) flagcnt = 0;
        if (col == 0) {                 // one writer lane per blk-group
#pragma unroll
            for (int r = 0; r < 4; ++r) {
                const int tok = Tt * 16 + blk * 4 + r;  // D row = blk*4+r
                candd [Hh * 32 + tok] = bs[r];
                candd2[Hh * 32 + tok] = bs2[r];
                candk [Hh * 32 + tok] = bk[r];
            }
        }
        __syncthreads();
        if (t < 32) {                   // final merge over the 2 code halves
            float best = 1e30f, sec = 1e30f; int bkk = -1;
#pragma unroll
            for (int c = 0; c < 2; ++c) {
                const float d  = candd [c * 32 + t];
                const float d2 = candd2[c * 32 + t];
                const int   k  = candk [c * 32 + t];
                const bool wn = (d < best) || (d == best && k < bkk);
                const float nw = fminf(sec, fminf(best, d2));
                const float nl = fminf(sec, d);
                sec  = wn ? nw : nl;
                bkk  = wn ? k : bkk;
                best = wn ? d : best;
            }
            bks[t] = bkk;
            const float* yr = &ybuf[t * 132 + l * 16];
            float n2 = 0.f;
#pragma unroll
            for (int c = 0; c < 16; ++c) n2 = fmaf(yr[c], yr[c], n2);
            if ((sec - best < TAU) || (n2 < 1e-3f)) {
                const int p = atomicAdd(&flagcnt, 1); flist[p] = t;
            }
        }
        __syncthreads();

        // ---- rare fp64 recheck (exact reference argmin) ----
        const int nf = flagcnt;
#pragma unroll 1
        for (int f = 0; f < nf; ++f) {
            const int tok = flist[f];
            double* rpd = stag_d;
            {
                const int c = t & 15, ch = t >> 4;
                const float* gz = z_e + (size_t)(tok0g + tok) * 1024 + ch * 64;
                const float* wp = Wd + ((size_t)l * 16 + c) * 1024 + ch * 64;
                double pd = 0.0;
                for (int dd = 0; dd < 64; ++dd)
                    pd = fma((double)gz[dd], (double)wp[dd], pd);
                rpd[c * 16 + ch] = pd;
            }
            __syncthreads();
            if (t < 16) {
                double y = hv64[l * 16 + t];
#pragma unroll
                for (int ch = 0; ch < 16; ++ch) y += rpd[t * 16 + ch];
                for (int j = 0; j < l; ++j) {
                    const int bkj = bkhist[tok * 8 + j];
                    const float* qv = cb + ((size_t)j * 1024 + bkj) * 16;
                    const double* gp = G64 + (size_t)(j * 8 + l) * 256 + t;
                    double s = 0.0;
#pragma unroll
                    for (int a = 0; a < 16; ++a)
                        s = fma((double)qv[a], gp[a * 16], s);
                    y -= s;
                }
                rpd[256 + t] = y;
            }
            __syncthreads();
            if (t == 0) {
                double n2 = 0.0;
#pragma unroll
                for (int c = 0; c < 16; ++c) n2 = fma(rpd[256 + c], rpd[256 + c], n2);
                const double iv = 1.0 / fmax(sqrt(n2), 1e-12);
#pragma unroll
                for (int c = 0; c < 16; ++c) rpd[272 + c] = rpd[256 + c] * iv;
            }
            __syncthreads();
            {
                double bd_ = 1e300; int bk_ = -1;
#pragma unroll
                for (int q = 0; q < 4; ++q) {
                    const int k = q * 256 + t;
                    const double* row = cbn64 + (size_t)(l * 1024 + k) * 17;
                    double dot = 0.0;
#pragma unroll
                    for (int c = 0; c < 16; ++c) dot = fma(row[c], rpd[272 + c], dot);
                    const double s = fma(-2.0, dot, row[16]);
                    if (s < bd_) { bd_ = s; bk_ = k; }
                }
                rpd[288 + t] = bd_;
                ((int*)&rpd[544])[t] = bk_;
            }
            __syncthreads();
            if (t == 0) {
                double bd_ = 1e300; int bk_ = -1;
                for (int i = 0; i < 256; ++i) {
                    const double d = rpd[288 + i];
                    const int k = ((int*)&rpd[544])[i];
                    if (d < bd_ || (d == bd_ && k < bk_)) { bd_ = d; bk_ = k; }
                }
                bks[tok] = bk_;
            }
            __syncthreads();
        }

        // ---- outputs, loss ----
        if (t < 32) {
            const int bk_ = bks[t];
            bkhist[t * 8 + l] = bk_;
            const float4* qp = (const float4*)(cb + ((size_t)l * 1024 + bk_) * 16);
            const float4 q0 = qp[0], q1 = qp[1], q2 = qp[2], q3 = qp[3];
            float* op = out0 + (size_t)(tok0g + t) * 128 + l * 16;
            ((float4*)op)[0] = q0; ((float4*)op)[1] = q1;
            ((float4*)op)[2] = q2; ((float4*)op)[3] = q3;
            out1[(size_t)(tok0g + t) * 8 + l] = (float)bk_;
            const float qf[16] = {q0.x,q0.y,q0.z,q0.w, q1.x,q1.y,q1.z,q1.w,
                                  q2.x,q2.y,q2.z,q2.w, q3.x,q3.y,q3.z,q3.w};
#pragma unroll
            for (int a = 0; a < 16; ++a) zqs[t * 17 + a] = qf[a];
            const float* yr = &ybuf[t * 132 + l * 16];
#pragma unroll
            for (int c = 0; c < 16; ++c) {
                const float d = yr[c] - qf[c];
                lacc += (double)d * (double)d;
            }
        }
        __syncthreads();

        // ---- corrections: ybuf[tok][ii*16+b] -= sum_a zq[a]*G32[l][ii][a][b] ----
        if (l < 7) {
            {
                const int total = (7 - l) * 256;
                for (int idx = t; idx < total; idx += 256) {
                    const int ii = l + 1 + (idx >> 8);
                    stag[idx] = G32[(size_t)(l * 8 + ii) * 256 + (idx & 255)];
                }
            }
            __syncthreads();
            const int part = t >> 5, tok = t & 31;
            const int ii = l + 1 + part;
            if (ii < 8) {
                float zql[16];
#pragma unroll
                for (int a = 0; a < 16; ++a) zql[a] = zqs[tok * 17 + a];
                const float* gb = &stag[part * 256];
                float corr[16];
#pragma unroll
                for (int x = 0; x < 16; ++x) corr[x] = 0.f;
#pragma unroll
                for (int a = 0; a < 16; ++a) {
                    const float4 g0 = *(const float4*)&gb[a * 16];
                    const float4 g1 = *(const float4*)&gb[a * 16 + 4];
                    const float4 g2 = *(const float4*)&gb[a * 16 + 8];
                    const float4 g3 = *(const float4*)&gb[a * 16 + 12];
                    const float za = zql[a];
                    corr[0]  = fmaf(za, g0.x, corr[0]);  corr[1]  = fmaf(za, g0.y, corr[1]);
                    corr[2]  = fmaf(za, g0.z, corr[2]);  corr[3]  = fmaf(za, g0.w, corr[3]);
                    corr[4]  = fmaf(za, g1.x, corr[4]);  corr[5]  = fmaf(za, g1.y, corr[5]);
                    corr[6]  = fmaf(za, g1.z, corr[6]);  corr[7]  = fmaf(za, g1.w, corr[7]);
                    corr[8]  = fmaf(za, g2.x, corr[8]);  corr[9]  = fmaf(za, g2.y, corr[9]);
                    corr[10] = fmaf(za, g2.z, corr[10]); corr[11] = fmaf(za, g2.w, corr[11]);
                    corr[12] = fmaf(za, g3.x, corr[12]); corr[13] = fmaf(za, g3.y, corr[13]);
                    corr[14] = fmaf(za, g3.z, corr[14]); corr[15] = fmaf(za, g3.w, corr[15]);
                }
                float* yr = &ybuf[tok * 132 + ii * 16];
#pragma unroll
                for (int v = 0; v < 4; ++v) {
                    float4 y4 = *(float4*)&yr[v * 4];
                    y4.x -= corr[v * 4 + 0]; y4.y -= corr[v * 4 + 1];
                    y4.z -= corr[v * 4 + 2]; y4.w -= corr[v * 4 + 3];
                    *(float4*)&yr[v * 4] = y4;
                }
            }
        }
    }

    if (t < 64) {
#pragma unroll
        for (int off = 32; off > 0; off >>= 1) lacc += __shfl_down(lacc, off);
        if (t == 0) atomicAdd(wacc, lacc);
    }
}

__global__ void __launch_bounds__(64) rvq_fin(const double* __restrict__ wacc,
                                              float* __restrict__ lossp) {
    if (threadIdx.x == 0) {
        const float v = (float)(wacc[0] * (1.0 / 524288.0));
        lossp[0] = v; lossp[1] = v; lossp[2] = 0.0f;
    }
}

extern "C" void kernel_launch(void* const* d_in, const int* in_sizes, int n_in,
                              void* d_out, int out_size, void* d_ws, size_t ws_size,
                              hipStream_t stream) {
    (void)in_sizes; (void)n_in; (void)ws_size;
    const float* z_e = (const float*)d_in[0];
    const float* Wd  = (const float*)d_in[1];
    const float* bd  = (const float*)d_in[2];
    const float* cb  = (const float*)d_in[3];
    const float* Wu  = (const float*)d_in[4];
    const float* bu  = (const float*)d_in[5];

    float* out0  = (float*)d_out;                      // (8,4096,128)
    float* out1  = out0 + (size_t)8 * 4096 * 128;      // (8,4096,8) codes
    float* lossp = out0 + (size_t)out_size - 3;        // commit, cbl, entropy

    char* ws = (char*)d_ws;
    double* wacc  = (double*)(ws + WS_WACC);
    double* hv64  = (double*)(ws + WS_HV64);
    double* G64   = (double*)(ws + WS_G64);
    double* cbn64 = (double*)(ws + WS_CBN64);
    unsigned short* cbf = (unsigned short*)(ws + WS_CBF);
    float*  G32   = (float*) (ws + WS_G32);
    float*  hv32  = (float*) (ws + WS_HV32);
    float*  Bmat  = (float*) (ws + WS_BMAT);
    double* sbu   = (double*)(ws + WS_SBU);

    rvq_prep1<<<193, 256, 0, stream>>>(cb, Wd, bu, cbn64, cbf, Bmat, sbu, wacc);
    rvq_prep2<<<72, 256, 0, stream>>>(Wu, Wd, bd, sbu, G64, G32, hv64, hv32);
    rvq_main<<<1024, 256, 0, stream>>>(z_e, Wd, cb, Bmat, hv32, hv64,
                                       cbf, cbn64, G32, G64, wacc, out0, out1);
    rvq_fin<<<1, 64, 0, stream>>>(wacc, lossp);
}

// Round 3
// 622.469 us; speedup vs baseline: 1.3873x; 1.0575x over previous
//
#include <hip/hip_runtime.h>
#include <math.h>

// ResidualVQ fused forward, MI355X (gfx950) — round 7.
// R6 post-mortem: 509us main; all pipes <=31% -> latency/serialization bound.
// GEMM was LDS-BW-bound (~130us: 33.5MB/CU LDS reads) + 128 barriers.
// R7: y-GEMM on MFMA (bf16 hi/lo, 3-term split, err ~1e-5 << TAU guard),
// A-frags straight from z_e (in-reg convert), B-frags from prebuilt
// pre-swizzled Bf in L2 -> ZERO LDS, ZERO barriers in GEMM.
// Scan: wave-per-quarter (both token halves) halves codebook L2 traffic;
// normalize in-register via shfl_xor (znbuf deleted). Preps merged into one
// kernel; Bmat transpose (4B stores @ stride 512B) replaced by coalesced Bf.

#define TAU 3e-4f

// ws byte offsets
#define WS_WACC   0
#define WS_HV64   64
#define WS_G64    2048
#define WS_CBN64  133120
#define WS_CBF    1247232   // 8192 codes x 32 ushort (bf16 hi|lo) = 512KB
#define WS_G32    1902592
#define WS_HV32   1968128
#define WS_BF     1968640   // B-fragments: hi 256KB | lo 256KB (pre-swizzled)
#define BF_LO_OFF 131072    // ushorts

typedef __attribute__((ext_vector_type(8))) short short8v;
typedef __attribute__((ext_vector_type(4))) float f32x4;

__device__ __forceinline__ unsigned short bf16_rne(float x) {
    unsigned u = __float_as_uint(x);
    u += 0x7FFFu + ((u >> 16) & 1u);
    return (unsigned short)(u >> 16);
}
__device__ __forceinline__ float bf16_to_f32(unsigned short h) {
    return __uint_as_float(((unsigned)h) << 16);
}

// ============================ prep (merged) ============================
// blocks: [0,32) cbn64+cbf | [32,96) Bf | [96,160) G | [160,168) hv | 168 zero
__global__ void __launch_bounds__(256) rvq_prep(
    const float* __restrict__ cb, const float* __restrict__ Wd,
    const float* __restrict__ Wu, const float* __restrict__ bd,
    const float* __restrict__ bu,
    double* __restrict__ cbn64, unsigned short* __restrict__ cbf,
    unsigned short* __restrict__ Bf,
    double* __restrict__ G64, float* __restrict__ G32,
    double* __restrict__ hv64, float* __restrict__ hv32,
    double* __restrict__ wacc)
{
    __shared__ double sm2[1200];
    float* smf = (float*)sm2;
    const int b = blockIdx.x, t = threadIdx.x;
    if (b < 32) {                       // normalized codebook fp64 + bf16 hi/lo
        const int idx = b * 256 + t;    // l*1024+k
        const float* cp = cb + (size_t)idx * 16;
        double v[16]; double n = 0.0;
#pragma unroll
        for (int c = 0; c < 16; ++c) { v[c] = (double)cp[c]; n = fma(v[c], v[c], n); }
        const double iv = 1.0 / fmax(sqrt(n), 1e-12);
        double* r64 = cbn64 + (size_t)idx * 17;
        unsigned short* cf = cbf + (size_t)idx * 32;
        double c2 = 0.0;
#pragma unroll
        for (int c = 0; c < 16; ++c) {
            const double x = v[c] * iv;
            c2 = fma(x, x, c2);
            r64[c] = x;
            const float xf = (float)x;
            const unsigned short hh = bf16_rne(xf);
            cf[c] = hh;
            cf[16 + c] = bf16_rne(xf - bf16_to_f32(hh));
        }
        r64[16] = c2;
    } else if (b < 96) {                // Bf: pre-swizzled bf16 hi/lo B-frags
        const int u = (b - 32) * 4 + (t >> 6);   // 0..255
        const int lane = t & 63;
        const int ks = u >> 3, ctg = u & 7;
        const int ic = ctg * 16 + (lane & 15);
        const int kb = ks * 32 + (lane >> 4) * 8;
        const float* wp = Wd + (size_t)ic * 1024 + kb;
        const float4 w0 = *(const float4*)wp;
        const float4 w1 = *(const float4*)(wp + 4);
        const float wv[8] = {w0.x, w0.y, w0.z, w0.w, w1.x, w1.y, w1.z, w1.w};
        unsigned short* dst = Bf + ((size_t)(ks * 8 + ctg) * 64 + lane) * 8;
#pragma unroll
        for (int i = 0; i < 8; ++i) {
            const unsigned short hh = bf16_rne(wv[i]);
            dst[i] = hh;
            dst[BF_LO_OFF + i] = bf16_rne(wv[i] - bf16_to_f32(hh));
        }
    } else if (b < 160) {               // G[j][i] = WuT_j . WdT_i (fp64)
        const int j = (b - 96) >> 3, i = (b - 96) & 7;
        if (j >= i) return;
        float* Aus = smf;               // [64][20] Wu[j, d, a]
        float* Bds = smf + 1280;        // [16][68] Wd[i, b, d]
        const int a = t >> 4, bb = t & 15;
        double s = 0.0;
        for (int ch = 0; ch < 16; ++ch) {
            __syncthreads();
            {
                const int dd = t >> 2, a4 = (t & 3) * 4;
                const float4 v = *(const float4*)(Wu + (size_t)j * 16384
                                  + (size_t)(ch * 64 + dd) * 16 + a4);
                *(float4*)&Aus[dd * 20 + a4] = v;
                const int br = t >> 4, d4 = (t & 15) * 4;
                const float4 w = *(const float4*)(Wd + (size_t)i * 16384
                                  + (size_t)br * 1024 + ch * 64 + d4);
                *(float4*)&Bds[br * 68 + d4] = w;
            }
            __syncthreads();
#pragma unroll
            for (int dd = 0; dd < 64; ++dd)
                s = fma((double)Aus[dd * 20 + a], (double)Bds[bb * 68 + dd], s);
        }
        G64[(size_t)(j * 8 + i) * 256 + t] = s;
        G32[(size_t)(j * 8 + i) * 256 + t] = (float)s;
    } else if (b < 168) {               // hv row i (sbu computed inline)
        const int i = b - 160;
        const int dq = t >> 4, bb = t & 15;
        const float* wp = Wd + (size_t)i * 16384 + (size_t)bb * 1024 + dq * 64;
        const float* bup = bu + dq * 64;
        double s = 0.0;
        for (int dd = 0; dd < 64; ++dd) {
            double sb = 0.0;
            for (int j = 0; j < i; ++j) sb += (double)bup[j * 1024 + dd];
            s = fma(sb, (double)wp[dd], s);
        }
        sm2[dq * 20 + bb] = s;
        __syncthreads();
        if (t < 16) {
            double s2 = 0.0;
#pragma unroll
            for (int q = 0; q < 16; ++q) s2 += sm2[q * 20 + t];
            const double h = (double)bd[i * 16 + t] - s2;
            hv64[i * 16 + t] = h; hv32[i * 16 + t] = (float)h;
        }
    } else {
        if (t == 0) wacc[0] = 0.0;
    }
}

// ============================ main ============================
// 1024 blocks x 256 threads, 32 tokens/block, ~29KB LDS -> 4 blocks/CU.
__global__ void __launch_bounds__(256, 4) rvq_main(
    const float* __restrict__ z_e, const float* __restrict__ Wd,
    const float* __restrict__ cb,
    const unsigned short* __restrict__ Bf, const float* __restrict__ hv32,
    const double* __restrict__ hv64,
    const unsigned short* __restrict__ cbf, const double* __restrict__ cbn64,
    const float* __restrict__ G32, const double* __restrict__ G64,
    double* __restrict__ wacc,
    float* __restrict__ out0, float* __restrict__ out1)
{
    __shared__ __attribute__((aligned(16))) double stag_d[896]; // 7KB union:
                                        // recheck (672 d) / G32 staging (1792 f)
    __shared__ float ybuf[32 * 132];    // 16.9KB
    __shared__ float candd[128], candd2[128];
    __shared__ int   candk[128];
    __shared__ float zqs[32 * 17];
    __shared__ int   bkhist[256];
    __shared__ int   bks[32], flist[32];
    __shared__ int   flagcnt;
    float* stag = reinterpret_cast<float*>(stag_d);

    const int t = threadIdx.x;
    const int tok0g = blockIdx.x * 32;
    const int wq = t >> 6, lane = t & 63;
    const int blk = lane >> 4, col = lane & 15, kh = blk & 1;
    const bool lolane = blk >= 2;

    // ---------------- GEMM: y = z_e . WdT + hv (MFMA, no LDS, no barriers) ----
    // wave (Ch=wq>>1, Tt=wq&1): 16-token half x 64-col half; 4 accs of 16x16.
    // Per K=32 step: A from z_e (in-reg bf16 hi/lo), B from pre-swizzled Bf.
    {
        const int Ch = wq >> 1, Tt = wq & 1;
        const float* zrow = z_e + (size_t)(tok0g + Tt * 16 + col) * 1024 + blk * 8;
        const unsigned short* bfh = Bf + ((size_t)(Ch * 4) * 64 + lane) * 8;
        f32x4 acc[4];
#pragma unroll
        for (int ct = 0; ct < 4; ++ct) acc[ct] = (f32x4){0.f, 0.f, 0.f, 0.f};

#pragma unroll 2
        for (int ks = 0; ks < 32; ++ks) {
            const float4 a0 = *(const float4*)(zrow + ks * 32);
            const float4 a1 = *(const float4*)(zrow + ks * 32 + 4);
            const float av[8] = {a0.x, a0.y, a0.z, a0.w, a1.x, a1.y, a1.z, a1.w};
            short8v ah, al;
#pragma unroll
            for (int i = 0; i < 8; ++i) {
                const unsigned short hh = bf16_rne(av[i]);
                ah[i] = (short)hh;
                al[i] = (short)bf16_rne(av[i] - bf16_to_f32(hh));
            }
            const unsigned short* bp = bfh + (size_t)ks * 4096;
#pragma unroll
            for (int ct = 0; ct < 4; ++ct) {
                const short8v bh = *(const short8v*)(bp + ct * 512);
                const short8v bl = *(const short8v*)(bp + BF_LO_OFF + ct * 512);
                acc[ct] = __builtin_amdgcn_mfma_f32_16x16x32_bf16(ah, bh, acc[ct], 0, 0, 0);
                acc[ct] = __builtin_amdgcn_mfma_f32_16x16x32_bf16(ah, bl, acc[ct], 0, 0, 0);
                acc[ct] = __builtin_amdgcn_mfma_f32_16x16x32_bf16(al, bh, acc[ct], 0, 0, 0);
            }
        }
        // epilogue: C row=(lane>>4)*4+r (token), col=lane&15 (ic) -> ybuf
#pragma unroll
        for (int ct = 0; ct < 4; ++ct) {
            const float hvv = hv32[Ch * 64 + ct * 16 + col];
#pragma unroll
            for (int r = 0; r < 4; ++r)
                ybuf[(Tt * 16 + blk * 4 + r) * 132 + Ch * 64 + ct * 16 + col]
                    = acc[ct][r] + hvv;
        }
    }

    // ---------------- layer loop ----------------
    double lacc = 0.0;
    const int q = wq;                   // wave = codebook quarter
#pragma unroll 1
    for (int l = 0; l < 8; ++l) {
        __syncthreads();                // ybuf (GEMM epilogue / prev corrections)

        // ---- normalize + A-frags (both token halves), fully in-register ----
        short8v af[2];
#pragma unroll
        for (int h = 0; h < 2; ++h) {
            const float* yp = &ybuf[(h * 16 + col) * 132 + l * 16 + kh * 8];
            const float4 y0 = *(const float4*)yp;
            const float4 y1 = *(const float4*)(yp + 4);
            const float yv[8] = {y0.x, y0.y, y0.z, y0.w, y1.x, y1.y, y1.z, y1.w};
            float p = 0.f;
#pragma unroll
            for (int i = 0; i < 8; ++i) p = fmaf(yv[i], yv[i], p);
            const float n2 = p + __shfl_xor(p, 16);
            const float iv = 1.0f / fmaxf(sqrtf(n2), 1e-12f);
#pragma unroll
            for (int i = 0; i < 8; ++i) {
                const float x = -2.f * (yv[i] * iv);
                const unsigned short hh = bf16_rne(x);
                af[h][i] = (short)(lolane ? bf16_rne(x - bf16_to_f32(hh)) : hh);
            }
        }

        // ---- distance scan: quarter q, 16 tiles, both token halves ----
        float bs[2][4], bs2[2][4]; int bk[2][4];
#pragma unroll
        for (int h = 0; h < 2; ++h)
#pragma unroll
            for (int r = 0; r < 4; ++r) { bs[h][r] = 1e30f; bs2[h][r] = 1e30f; bk[h][r] = -1; }
        const unsigned short* cbp = cbf + ((size_t)(l * 1024 + q * 256 + col)) * 32;
        const unsigned short* p1 = cbp + kh * 8;        // ch half
        const unsigned short* p2 = cbp + 16 + kh * 8;   // cl half (blk<2)
#pragma unroll 2
        for (int tile = 0; tile < 16; ++tile) {
            const short8v b1 = *(const short8v*)(p1 + tile * 512);
            short8v b2 = {};
            if (!lolane) b2 = *(const short8v*)(p2 + tile * 512);
            f32x4 aa[2];
            aa[0] = (f32x4){0.f, 0.f, 0.f, 0.f};
            aa[0] = __builtin_amdgcn_mfma_f32_16x16x32_bf16(af[0], b1, aa[0], 0, 0, 0);
            aa[0] = __builtin_amdgcn_mfma_f32_16x16x32_bf16(af[0], b2, aa[0], 0, 0, 0);
            aa[1] = (f32x4){0.f, 0.f, 0.f, 0.f};
            aa[1] = __builtin_amdgcn_mfma_f32_16x16x32_bf16(af[1], b1, aa[1], 0, 0, 0);
            aa[1] = __builtin_amdgcn_mfma_f32_16x16x32_bf16(af[1], b2, aa[1], 0, 0, 0);
            const int k = q * 256 + tile * 16 + col;
#pragma unroll
            for (int h = 0; h < 2; ++h)
#pragma unroll
                for (int r = 0; r < 4; ++r) {
                    const float s = aa[h][r];
                    const bool wn = s < bs[h][r];
                    bs2[h][r] = wn ? bs[h][r] : fminf(bs2[h][r], s);
                    bk[h][r]  = wn ? k : bk[h][r];
                    bs[h][r]  = wn ? s : bs[h][r];
                }
        }

        // ---- lexicographic top-2 merge across the 16 cols ----
#pragma unroll
        for (int m = 1; m <= 8; m <<= 1)
#pragma unroll
            for (int h = 0; h < 2; ++h)
#pragma unroll
                for (int r = 0; r < 4; ++r) {
                    const float ob = __shfl_xor(bs[h][r], m);
                    const float os = __shfl_xor(bs2[h][r], m);
                    const int   ok = __shfl_xor(bk[h][r], m);
                    const bool wn = (ob < bs[h][r]) || (ob == bs[h][r] && ok < bk[h][r]);
                    const float loser = wn ? bs[h][r] : ob;
                    bs2[h][r] = fminf(fminf(bs2[h][r], os), loser);
                    bs[h][r]  = wn ? ob : bs[h][r];
                    bk[h][r]  = wn ? ok : bk[h][r];
                }
        if (t == 0) flagcnt = 0;
        if (col == 0) {                 // one writer lane per blk-group
#pragma unroll
            for (int h = 0; h < 2; ++h)
#pragma unroll
                for (int r = 0; r < 4; ++r) {
                    const int tok = h * 16 + blk * 4 + r;
                    candd [q * 32 + tok] = bs[h][r];
                    candd2[q * 32 + tok] = bs2[h][r];
                    candk [q * 32 + tok] = bk[h][r];
                }
        }
        __syncthreads();
        if (t < 32) {                   // final merge over 4 quarters
            float best = 1e30f, sec = 1e30f; int bkk = -1;
#pragma unroll
            for (int c = 0; c < 4; ++c) {
                const float d  = candd [c * 32 + t];
                const float d2 = candd2[c * 32 + t];
                const int   k  = candk [c * 32 + t];
                const bool wn = (d < best) || (d == best && k < bkk);
                const float nw = fminf(sec, fminf(best, d2));
                const float nl = fminf(sec, d);
                sec  = wn ? nw : nl;
                bkk  = wn ? k : bkk;
                best = wn ? d : best;
            }
            bks[t] = bkk;
            const float* yr = &ybuf[t * 132 + l * 16];
            float n2 = 0.f;
#pragma unroll
            for (int c = 0; c < 16; ++c) n2 = fmaf(yr[c], yr[c], n2);
            if ((sec - best < TAU) || (n2 < 1e-3f)) {
                const int p = atomicAdd(&flagcnt, 1); flist[p] = t;
            }
        }
        __syncthreads();

        // ---- rare fp64 recheck (exact reference argmin) ----
        const int nf = flagcnt;
#pragma unroll 1
        for (int f = 0; f < nf; ++f) {
            const int tok = flist[f];
            double* rpd = stag_d;
            {
                const int c = t & 15, ch = t >> 4;
                const float* gz = z_e + (size_t)(tok0g + tok) * 1024 + ch * 64;
                const float* wp = Wd + ((size_t)l * 16 + c) * 1024 + ch * 64;
                double pd = 0.0;
                for (int dd = 0; dd < 64; ++dd)
                    pd = fma((double)gz[dd], (double)wp[dd], pd);
                rpd[c * 16 + ch] = pd;
            }
            __syncthreads();
            if (t < 16) {
                double y = hv64[l * 16 + t];
#pragma unroll
                for (int ch = 0; ch < 16; ++ch) y += rpd[t * 16 + ch];
                for (int j = 0; j < l; ++j) {
                    const int bkj = bkhist[tok * 8 + j];
                    const float* qv = cb + ((size_t)j * 1024 + bkj) * 16;
                    const double* gp = G64 + (size_t)(j * 8 + l) * 256 + t;
                    double s = 0.0;
#pragma unroll
                    for (int a = 0; a < 16; ++a)
                        s = fma((double)qv[a], gp[a * 16], s);
                    y -= s;
                }
                rpd[256 + t] = y;
            }
            __syncthreads();
            if (t == 0) {
                double n2 = 0.0;
#pragma unroll
                for (int c = 0; c < 16; ++c) n2 = fma(rpd[256 + c], rpd[256 + c], n2);
                const double iv = 1.0 / fmax(sqrt(n2), 1e-12);
#pragma unroll
                for (int c = 0; c < 16; ++c) rpd[272 + c] = rpd[256 + c] * iv;
            }
            __syncthreads();
            {
                double bd_ = 1e300; int bk_ = -1;
#pragma unroll
                for (int qq = 0; qq < 4; ++qq) {
                    const int k = qq * 256 + t;
                    const double* row = cbn64 + (size_t)(l * 1024 + k) * 17;
                    double dot = 0.0;
#pragma unroll
                    for (int c = 0; c < 16; ++c) dot = fma(row[c], rpd[272 + c], dot);
                    const double s = fma(-2.0, dot, row[16]);
                    if (s < bd_) { bd_ = s; bk_ = k; }
                }
                rpd[288 + t] = bd_;
                ((int*)&rpd[544])[t] = bk_;
            }
            __syncthreads();
            if (t == 0) {
                double bd_ = 1e300; int bk_ = -1;
                for (int i = 0; i < 256; ++i) {
                    const double d = rpd[288 + i];
                    const int k = ((int*)&rpd[544])[i];
                    if (d < bd_ || (d == bd_ && k < bk_)) { bd_ = d; bk_ = k; }
                }
                bks[tok] = bk_;
            }
            __syncthreads();
        }

        // ---- outputs, loss ----
        if (t < 32) {
            const int bk_ = bks[t];
            bkhist[t * 8 + l] = bk_;
            const float4* qp = (const float4*)(cb + ((size_t)l * 1024 + bk_) * 16);
            const float4 q0 = qp[0], q1 = qp[1], q2 = qp[2], q3 = qp[3];
            float* op = out0 + (size_t)(tok0g + t) * 128 + l * 16;
            ((float4*)op)[0] = q0; ((float4*)op)[1] = q1;
            ((float4*)op)[2] = q2; ((float4*)op)[3] = q3;
            out1[(size_t)(tok0g + t) * 8 + l] = (float)bk_;
            const float qf[16] = {q0.x,q0.y,q0.z,q0.w, q1.x,q1.y,q1.z,q1.w,
                                  q2.x,q2.y,q2.z,q2.w, q3.x,q3.y,q3.z,q3.w};
#pragma unroll
            for (int a = 0; a < 16; ++a) zqs[t * 17 + a] = qf[a];
            const float* yr = &ybuf[t * 132 + l * 16];
#pragma unroll
            for (int c = 0; c < 16; ++c) {
                const float d = yr[c] - qf[c];
                lacc += (double)d * (double)d;
            }
        }
        __syncthreads();

        // ---- corrections: ybuf[tok][ii*16+b] -= sum_a zq[a]*G32[l][ii][a][b] ----
        if (l < 7) {
            {
                const int total = (7 - l) * 256;
                for (int idx = t; idx < total; idx += 256) {
                    const int ii = l + 1 + (idx >> 8);
                    stag[idx] = G32[(size_t)(l * 8 + ii) * 256 + (idx & 255)];
                }
            }
            __syncthreads();
            const int part = t >> 5, tok = t & 31;
            const int ii = l + 1 + part;
            if (ii < 8) {
                float zql[16];
#pragma unroll
                for (int a = 0; a < 16; ++a) zql[a] = zqs[tok * 17 + a];
                const float* gb = &stag[part * 256];
                float corr[16];
#pragma unroll
                for (int x = 0; x < 16; ++x) corr[x] = 0.f;
#pragma unroll
                for (int a = 0; a < 16; ++a) {
                    const float4 g0 = *(const float4*)&gb[a * 16];
                    const float4 g1 = *(const float4*)&gb[a * 16 + 4];
                    const float4 g2 = *(const float4*)&gb[a * 16 + 8];
                    const float4 g3 = *(const float4*)&gb[a * 16 + 12];
                    const float za = zql[a];
                    corr[0]  = fmaf(za, g0.x, corr[0]);  corr[1]  = fmaf(za, g0.y, corr[1]);
                    corr[2]  = fmaf(za, g0.z, corr[2]);  corr[3]  = fmaf(za, g0.w, corr[3]);
                    corr[4]  = fmaf(za, g1.x, corr[4]);  corr[5]  = fmaf(za, g1.y, corr[5]);
                    corr[6]  = fmaf(za, g1.z, corr[6]);  corr[7]  = fmaf(za, g1.w, corr[7]);
                    corr[8]  = fmaf(za, g2.x, corr[8]);  corr[9]  = fmaf(za, g2.y, corr[9]);
                    corr[10] = fmaf(za, g2.z, corr[10]); corr[11] = fmaf(za, g2.w, corr[11]);
                    corr[12] = fmaf(za, g3.x, corr[12]); corr[13] = fmaf(za, g3.y, corr[13]);
                    corr[14] = fmaf(za, g3.z, corr[14]); corr[15] = fmaf(za, g3.w, corr[15]);
                }
                float* yr = &ybuf[tok * 132 + ii * 16];
#pragma unroll
                for (int v = 0; v < 4; ++v) {
                    float4 y4 = *(float4*)&yr[v * 4];
                    y4.x -= corr[v * 4 + 0]; y4.y -= corr[v * 4 + 1];
                    y4.z -= corr[v * 4 + 2]; y4.w -= corr[v * 4 + 3];
                    *(float4*)&yr[v * 4] = y4;
                }
            }
        }
    }

    if (t < 64) {
#pragma unroll
        for (int off = 32; off > 0; off >>= 1) lacc += __shfl_down(lacc, off);
        if (t == 0) atomicAdd(wacc, lacc);
    }
}

__global__ void __launch_bounds__(64) rvq_fin(const double* __restrict__ wacc,
                                              float* __restrict__ lossp) {
    if (threadIdx.x == 0) {
        const float v = (float)(wacc[0] * (1.0 / 524288.0));
        lossp[0] = v; lossp[1] = v; lossp[2] = 0.0f;
    }
}

extern "C" void kernel_launch(void* const* d_in, const int* in_sizes, int n_in,
                              void* d_out, int out_size, void* d_ws, size_t ws_size,
                              hipStream_t stream) {
    (void)in_sizes; (void)n_in; (void)ws_size;
    const float* z_e = (const float*)d_in[0];
    const float* Wd  = (const float*)d_in[1];
    const float* bd  = (const float*)d_in[2];
    const float* cb  = (const float*)d_in[3];
    const float* Wu  = (const float*)d_in[4];
    const float* bu  = (const float*)d_in[5];

    float* out0  = (float*)d_out;                      // (8,4096,128)
    float* out1  = out0 + (size_t)8 * 4096 * 128;      // (8,4096,8) codes
    float* lossp = out0 + (size_t)out_size - 3;        // commit, cbl, entropy

    char* ws = (char*)d_ws;
    double* wacc  = (double*)(ws + WS_WACC);
    double* hv64  = (double*)(ws + WS_HV64);
    double* G64   = (double*)(ws + WS_G64);
    double* cbn64 = (double*)(ws + WS_CBN64);
    unsigned short* cbf = (unsigned short*)(ws + WS_CBF);
    float*  G32   = (float*) (ws + WS_G32);
    float*  hv32  = (float*) (ws + WS_HV32);
    unsigned short* Bf = (unsigned short*)(ws + WS_BF);

    rvq_prep<<<169, 256, 0, stream>>>(cb, Wd, Wu, bd, bu, cbn64, cbf, Bf,
                                      G64, G32, hv64, hv32, wacc);
    rvq_main<<<1024, 256, 0, stream>>>(z_e, Wd, cb, Bf, hv32, hv64,
                                       cbf, cbn64, G32, G64, wacc, out0, out1);
    rvq_fin<<<1, 64, 0, stream>>>(wacc, lossp);
}